// Round 8
// baseline (305.156 us; speedup 1.0000x reference)
//
#include <hip/hip_runtime.h>
#include <hip/hip_fp16.h>

#define NN 100000
#define NE 1250000
#define NBIN 512
#define RBIN 196          // ceil(NN/NBIN); bin b covers nodes [b*196, b*196+196)
#define PAD 16            // counter padding: 16 ints = 64B line
#define CAP 4096          // binD LDS edge-staging capacity (int2 = 32KB)
#define EPB 4096          // binC edges per block
#define EPT 16            // EPB/256

__device__ __forceinline__ int eidx(const int* __restrict__ e32, int f, int i){
    return f ? e32[2*(size_t)i] : e32[i];
}

// one-wave exclusive scan of the 512 global bin counters into LDS boff[]
__device__ __forceinline__ void scan_bins(const int* __restrict__ binCnt, int* __restrict__ boff){
    if(threadIdx.x < 64){
        int b0 = threadIdx.x*8;
        int pre[8]; int run = 0;
        #pragma unroll
        for(int i = 0; i < 8; ++i){ pre[i] = run; run += binCnt[(b0+i)*PAD]; }
        int inc = run;
        for(int o = 1; o < 64; o <<= 1){
            int u = __shfl_up(inc, o, 64);
            if(threadIdx.x >= (unsigned)o) inc += u;
        }
        int excl = inc - run;
        #pragma unroll
        for(int i = 0; i < 8; ++i) boff[b0+i] = excl + pre[i];
    }
    __syncthreads();
}

// ---------------- pass A: per-bin edge counts (LDS histogram), inline dtype detect ----------------
__global__ __launch_bounds__(256) void binA_k(const int* __restrict__ e32, int* __restrict__ binCnt){
    __shared__ int h[NBIN];
    __shared__ int flg;
    for(int t = threadIdx.x; t < NBIN; t += 256) h[t] = 0;
    if(threadIdx.x < 64){
        int v = e32[2*threadIdx.x + 1];
        unsigned long long b = __ballot(v != 0);
        if(threadIdx.x == 0) flg = (b == 0ULL) ? 1 : 0;
    }
    __syncthreads();
    const int f = flg;
    int base = blockIdx.x * 2048;
    #pragma unroll
    for(int k = 0; k < 8; ++k){
        int i = base + k*256 + threadIdx.x;
        if(i < NE){
            int d = eidx(e32, f, NE + i);
            atomicAdd(&h[d / RBIN], 1);
        }
    }
    __syncthreads();
    for(int t = threadIdx.x; t < NBIN; t += 256){
        int v = h[t];
        if(v) atomicAdd(&binCnt[t*PAD], v);
    }
}

// ---------------- pass C: block multi-split scatter into dst-bins (inline scan + detect) ----------------
__global__ __launch_bounds__(256) void binC_k(const int* __restrict__ e32, const int* __restrict__ binCnt,
                                              int* __restrict__ binCur, int2* __restrict__ bins){
    __shared__ int2 ST[EPB];          // 32KB staged edges, grouped by bin
    __shared__ int hist[NBIN];
    __shared__ int lstart[NBIN];
    __shared__ int gbase[NBIN];
    __shared__ int cur[NBIN];
    __shared__ int boff[NBIN];
    __shared__ int flg;
    const int t = threadIdx.x;
    const int e0 = blockIdx.x * EPB;
    const int n = min(EPB, NE - e0);

    for(int b = t; b < NBIN; b += 256){ hist[b] = 0; cur[b] = 0; }
    if(t < 64){
        int v = e32[2*t + 1];
        unsigned long long b = __ballot(v != 0);
        if(t == 0) flg = (b == 0ULL) ? 1 : 0;
    }
    __syncthreads();
    const int f = flg;
    scan_bins(binCnt, boff);

    // load edges to registers + LDS histogram
    int2 ed[EPT];
    #pragma unroll
    for(int k = 0; k < EPT; ++k){
        int i = k*256 + t;
        if(i < n){
            ed[k].x = eidx(e32, f, e0 + i);
            ed[k].y = eidx(e32, f, NE + e0 + i);
            atomicAdd(&hist[ed[k].y / RBIN], 1);
        }
    }
    __syncthreads();

    // single-wave exclusive scan of block-local hist
    if(t < 64){
        int b0 = t*8;
        int pre[8]; int run = 0;
        #pragma unroll
        for(int i = 0; i < 8; ++i){ pre[i] = run; run += hist[b0 + i]; }
        int inc = run;
        for(int o = 1; o < 64; o <<= 1){
            int u = __shfl_up(inc, o, 64);
            if(t >= o) inc += u;
        }
        int excl = inc - run;
        #pragma unroll
        for(int i = 0; i < 8; ++i) lstart[b0 + i] = excl + pre[i];
    }
    // reserve contiguous global ranges (one atomic per bin per block)
    for(int b = t; b < NBIN; b += 256) gbase[b] = boff[b] + atomicAdd(&binCur[b*PAD], hist[b]);
    __syncthreads();

    // scatter into LDS grouped by bin
    #pragma unroll
    for(int k = 0; k < EPT; ++k){
        int i = k*256 + t;
        if(i < n){
            int b = ed[k].y / RBIN;
            int lo = atomicAdd(&cur[b], 1);
            ST[lstart[b] + lo] = ed[k];
        }
    }
    __syncthreads();

    // linear copy-out: consecutive staged entries in a bin -> consecutive global slots
    for(int i = t; i < n; i += 256){
        int2 e = ST[i];
        int b = e.y / RBIN;
        bins[gbase[b] + (i - lstart[b])] = e;
    }
}

// ---------------- pass D: per-bin CSR build (rp, dinv, csr_src), inline scan ----------------
__global__ __launch_bounds__(256) void binD_k(const int2* __restrict__ bins, const int* __restrict__ binCnt,
                                              int* __restrict__ rp, float* __restrict__ dinv,
                                              int* __restrict__ csr_src){
    __shared__ int2 ES[CAP];
    __shared__ int hist[256];
    __shared__ int sc[256];
    __shared__ int cur[256];
    __shared__ int boff[NBIN];
    const int b = blockIdx.x;
    const int t = threadIdx.x;
    if(b == NBIN-1 && t == 0) rp[NN] = NE;
    const int nbase = b * RBIN;
    if(nbase >= NN) return;                      // empty trailing bin
    const int nend = min(nbase + RBIN, NN);
    const int nr = nend - nbase;
    hist[t] = 0; cur[t] = 0;
    __syncthreads();
    scan_bins(binCnt, boff);
    const int off0 = boff[b];
    const int cnt  = binCnt[b*PAD];

    const bool single = (cnt <= CAP);
    // histogram phase
    for(int c0 = 0; c0 < cnt; c0 += CAP){
        int n = min(CAP, cnt - c0);
        for(int i = t; i < n; i += 256) ES[i] = bins[off0 + c0 + i];
        __syncthreads();
        for(int i = t; i < n; i += 256) atomicAdd(&hist[ES[i].y - nbase], 1);
        __syncthreads();
    }
    // exclusive scan of hist into sc
    int v = hist[t];
    sc[t] = v; __syncthreads();
    for(int off = 1; off < 256; off <<= 1){
        int u = (t >= off) ? sc[t - off] : 0;
        __syncthreads();
        sc[t] += u;
        __syncthreads();
    }
    int excl = sc[t] - v;
    sc[t] = excl;
    if(t < nr){
        rp[nbase + t]   = off0 + excl;
        dinv[nbase + t] = rsqrtf((float)(v + 1));   // +1 = self loop
    }
    __syncthreads();
    // scatter phase (ES still valid if single chunk)
    for(int c0 = 0; c0 < cnt; c0 += CAP){
        int n = min(CAP, cnt - c0);
        if(!single){
            for(int i = t; i < n; i += 256) ES[i] = bins[off0 + c0 + i];
            __syncthreads();
        }
        for(int i = t; i < n; i += 256){
            int dl = ES[i].y - nbase;
            int p = atomicAdd(&cur[dl], 1);
            csr_src[off0 + sc[dl] + p] = ES[i].x;
        }
        if(!single) __syncthreads();
    }
}

// ---------------- dense GEMM, K-tiled: out[row] = fp16( (A@W)[row] * dinv[row] ) ----------------
template<int K, int NC, int KT, bool RELU>
__global__ __launch_bounds__(256) void gemm_k(const float* __restrict__ A, const float* __restrict__ W,
                                              const float* __restrict__ dinv,
                                              __half* __restrict__ out, int M){
    constexpr int CHT = KT/4;          // float4 chunks per row per K-tile
    constexpr int CMASK = CHT - 1;
    __shared__ float Xs[64*KT];
    __shared__ float Ws[KT*NC];
    const int tid  = threadIdx.x;
    const int base = blockIdx.x * 64;
    const int tx = tid & 15, ty = tid >> 4;
    const int c0 = tx * 4;
    float acc[4][4] = {};

    for(int k0 = 0; k0 < K; k0 += KT){
        // Ws staging: rows k0..k0+KT
        {
            const float4* Wv = (const float4*)(W + k0*NC);
            float4* Wsv = (float4*)Ws;
            for(int i = tid; i < KT*NC/4; i += 256) Wsv[i] = Wv[i];
        }
        // Xs staging: float4, chunk-rotate swizzle
        {
            const int ch = tid & (CHT - 1);
            const int r0 = tid / CHT;
            constexpr int RSTEP = 256 / CHT;
            #pragma unroll
            for(int r = r0; r < 64; r += RSTEP){
                int row = base + r; if(row >= M) row = M - 1;
                float4 v = *(const float4*)&A[(size_t)row*K + k0 + ch*4];
                if(RELU){ v.x=fmaxf(v.x,0.f); v.y=fmaxf(v.y,0.f); v.z=fmaxf(v.z,0.f); v.w=fmaxf(v.w,0.f); }
                int sw = (ch + r) & CMASK;
                *(float4*)&Xs[r*KT + sw*4] = v;
            }
        }
        __syncthreads();

        if(c0 < NC){
            for(int k4 = 0; k4 < CHT; ++k4){
                float4 xs[4];
                #pragma unroll
                for(int i = 0; i < 4; ++i){
                    int r = ty*4 + i;
                    int sw = (k4 + r) & CMASK;
                    xs[i] = *(const float4*)&Xs[r*KT + (sw << 2)];
                }
                float4 wsv[4];
                #pragma unroll
                for(int kk = 0; kk < 4; ++kk) wsv[kk] = *(const float4*)&Ws[(k4*4 + kk)*NC + c0];
                #pragma unroll
                for(int kk = 0; kk < 4; ++kk){
                    const float* wp = (const float*)&wsv[kk];
                    #pragma unroll
                    for(int i = 0; i < 4; ++i){
                        float xv = ((const float*)&xs[i])[kk];
                        #pragma unroll
                        for(int j = 0; j < 4; ++j) acc[i][j] += xv * wp[j];
                    }
                }
            }
        }
        __syncthreads();
    }
    #pragma unroll
    for(int i = 0; i < 4; ++i){
        int row = base + ty*4 + i;
        if(row < M && c0 < NC){
            float dv = dinv[row];
            __half2 h01 = __floats2half2_rn(acc[i][0]*dv, acc[i][1]*dv);
            __half2 h23 = __floats2half2_rn(acc[i][2]*dv, acc[i][3]*dv);
            __half2* dst = (__half2*)&out[(size_t)row*NC + c0];
            dst[0] = h01;
            dst[1] = h23;
        }
    }
}

// ---------------- split CSR aggregation (F=64): 2 waves/node (channel halves), 8 lanes/edge ----------------
// G[v] = b + dinv[v]*(sum P[s] + P[v]); P fp16 pre-scaled by dinv; fp32 accum (pairwise fp16 pre-add).
__global__ __launch_bounds__(256) void aggs_k(const __half* __restrict__ P, const int* __restrict__ rp,
                                              const int* __restrict__ csr_src,
                                              const float* __restrict__ dinv, const float* __restrict__ bias,
                                              float* __restrict__ G){
    const int lane = threadIdx.x & 63;
    const int idx  = (blockIdx.x*256 + threadIdx.x) >> 6;   // global wave id
    const int v    = idx >> 1;
    const int half = idx & 1;
    if(v >= NN) return;
    const int g = lane >> 3;                      // edge-group 0..7
    const int q = lane & 7;                       // channel-quad within half
    const unsigned qo = (unsigned)(half*8 + q)*2; // half2 offset in row
    const __half2* __restrict__ P2 = (const __half2*)P;
    constexpr unsigned F2 = 32;

    const int beg = rp[v], end = rp[v + 1];
    float4 acc = make_float4(0.f, 0.f, 0.f, 0.f);
    if(g == 0){                                   // self-loop term
        __half2 a = P2[(unsigned)v*F2 + qo], b = P2[(unsigned)v*F2 + qo + 1];
        float2 fa = __half22float2(a), fb = __half22float2(b);
        acc = make_float4(fa.x, fa.y, fb.x, fb.y);
    }

    int j = beg;
    #pragma unroll 1
    for(; j + 16 <= end; j += 16){
        unsigned i0 = (unsigned)csr_src[j + g]    *F2 + qo;
        unsigned i1 = (unsigned)csr_src[j + 8 + g]*F2 + qo;
        __half2 a0 = P2[i0], b0 = P2[i0+1];
        __half2 a1 = P2[i1], b1 = P2[i1+1];
        __half2 sa = __hadd2(a0, a1), sb = __hadd2(b0, b1);
        float2 f0 = __half22float2(sa), f1 = __half22float2(sb);
        acc.x += f0.x; acc.y += f0.y; acc.z += f1.x; acc.w += f1.y;
    }
    if(j + 8 <= end){
        unsigned i0 = (unsigned)csr_src[j + g]*F2 + qo;
        __half2 a = P2[i0], b = P2[i0+1];
        float2 fa = __half22float2(a), fb = __half22float2(b);
        acc.x += fa.x; acc.y += fa.y; acc.z += fb.x; acc.w += fb.y;
        j += 8;
    }
    const int rem = end - j;                      // 0..7
    if(g < rem){
        unsigned i0 = (unsigned)csr_src[j + g]*F2 + qo;
        __half2 a = P2[i0], b = P2[i0+1];
        float2 fa = __half22float2(a), fb = __half22float2(b);
        acc.x += fa.x; acc.y += fa.y; acc.z += fb.x; acc.w += fb.y;
    }

    // reduce across the 8 edge-groups (butterfly over lane bits 3,4,5)
    #pragma unroll
    for(int m = 8; m <= 32; m <<= 1){
        acc.x += __shfl_xor(acc.x, m, 64);
        acc.y += __shfl_xor(acc.y, m, 64);
        acc.z += __shfl_xor(acc.z, m, 64);
        acc.w += __shfl_xor(acc.w, m, 64);
    }

    if(g == 0){
        const float d = dinv[v];
        float4 bb = *(const float4*)&bias[half*32 + q*4];
        float4 r;
        r.x = fmaf(acc.x, d, bb.x);
        r.y = fmaf(acc.y, d, bb.y);
        r.z = fmaf(acc.z, d, bb.z);
        r.w = fmaf(acc.w, d, bb.w);
        *(float4*)&G[(size_t)v*64 + half*32 + q*4] = r;
    }
}

// ---------------- final CSR aggregation (F=40) + fused log_softmax ----------------
__global__ __launch_bounds__(256) void agg40_k(const __half* __restrict__ P, const int* __restrict__ rp,
                                               const int* __restrict__ csr_src,
                                               const float* __restrict__ dinv, const float* __restrict__ bias,
                                               float* __restrict__ G){
    constexpr int F = 40;
    constexpr int NQ = 10;
    constexpr unsigned F2 = 20;
    const int lane = threadIdx.x & 63;
    const int v = (blockIdx.x*256 + threadIdx.x) >> 6;
    if(v >= NN) return;
    const int g = lane >> 4;                      // edge-group 0..3
    const int q = lane & 15;                      // channel-quad
    const bool qa = (q < NQ);
    const unsigned qo = (unsigned)q*2;
    const __half2* __restrict__ P2 = (const __half2*)P;

    const int beg = rp[v], end = rp[v + 1];
    float4 acc = make_float4(0.f, 0.f, 0.f, 0.f);
    if(g == 0 && qa){
        __half2 a = P2[(unsigned)v*F2 + qo], b = P2[(unsigned)v*F2 + qo + 1];
        float2 fa = __half22float2(a), fb = __half22float2(b);
        acc = make_float4(fa.x, fa.y, fb.x, fb.y);
    }

    int j = beg;
    #pragma unroll 1
    for(; j + 8 <= end; j += 8){
        unsigned i0 = (unsigned)csr_src[j + g]    *F2 + qo;
        unsigned i1 = (unsigned)csr_src[j + 4 + g]*F2 + qo;
        __half2 a0 = P2[i0], b0 = P2[i0+1];
        __half2 a1 = P2[i1], b1 = P2[i1+1];
        __half2 sa = __hadd2(a0, a1), sb = __hadd2(b0, b1);
        float2 f0 = __half22float2(sa), f1 = __half22float2(sb);
        acc.x += f0.x; acc.y += f0.y; acc.z += f1.x; acc.w += f1.y;
    }
    if(j + 4 <= end){
        unsigned i0 = (unsigned)csr_src[j + g]*F2 + qo;
        __half2 a = P2[i0], b = P2[i0+1];
        float2 fa = __half22float2(a), fb = __half22float2(b);
        acc.x += fa.x; acc.y += fa.y; acc.z += fb.x; acc.w += fb.y;
        j += 4;
    }
    const int rem = end - j;                      // 0..3
    if(g < rem){
        unsigned i0 = (unsigned)csr_src[j + g]*F2 + qo;
        __half2 a = P2[i0], b = P2[i0+1];
        float2 fa = __half22float2(a), fb = __half22float2(b);
        acc.x += fa.x; acc.y += fa.y; acc.z += fb.x; acc.w += fb.y;
    }

    #pragma unroll
    for(int m = 16; m <= 32; m <<= 1){
        acc.x += __shfl_xor(acc.x, m, 64);
        acc.y += __shfl_xor(acc.y, m, 64);
        acc.z += __shfl_xor(acc.z, m, 64);
        acc.w += __shfl_xor(acc.w, m, 64);
    }

    float4 r;
    const float d = dinv[v];
    if(g == 0 && qa){
        float4 bb = *(const float4*)&bias[q*4];
        r.x = fmaf(acc.x, d, bb.x);
        r.y = fmaf(acc.y, d, bb.y);
        r.z = fmaf(acc.z, d, bb.z);
        r.w = fmaf(acc.w, d, bb.w);
    }
    // fused log_softmax: butterfly over lane bits 0..3 (within 16-lane group); group 0 authoritative
    float lm = (g == 0 && qa) ? fmaxf(fmaxf(r.x, r.y), fmaxf(r.z, r.w)) : -3.402823466e38f;
    #pragma unroll
    for(int m = 1; m <= 8; m <<= 1) lm = fmaxf(lm, __shfl_xor(lm, m, 64));
    float ls = (g == 0 && qa)
             ? (__expf(r.x - lm) + __expf(r.y - lm) + __expf(r.z - lm) + __expf(r.w - lm)) : 0.0f;
    #pragma unroll
    for(int m = 1; m <= 8; m <<= 1) ls += __shfl_xor(ls, m, 64);
    if(g == 0 && qa){
        float lz = lm + __logf(ls);
        r.x -= lz; r.y -= lz; r.z -= lz; r.w -= lz;
        *(float4*)&G[(size_t)v*F + q*4] = r;
    }
}

extern "C" void kernel_launch(void* const* d_in, const int* in_sizes, int n_in,
                              void* d_out, int out_size, void* d_ws, size_t ws_size,
                              hipStream_t stream){
    const float* x   = (const float*)d_in[0];
    const int*   e32 = (const int*)  d_in[1];
    const float* W1  = (const float*)d_in[2];
    const float* b1  = (const float*)d_in[3];
    const float* W2  = (const float*)d_in[4];
    const float* b2  = (const float*)d_in[5];
    const float* W3  = (const float*)d_in[6];
    const float* b3  = (const float*)d_in[7];
    float* out = (float*)d_out;

    char* ws = (char*)d_ws;
    size_t off = 0;
    auto alloc = [&](size_t bytes) -> void* {
        void* p = ws + off;
        off = (off + bytes + 255) & ~(size_t)255;
        return p;
    };
    int*    binCnt = (int*)   alloc((size_t)NBIN*PAD*4);   // 32KB  (zeroed together
    int*    binCur = (int*)   alloc((size_t)NBIN*PAD*4);   // 32KB   with binCnt)
    int*    rp     = (int*)   alloc((size_t)(NN+1)*4);
    float*  dinv   = (float*) alloc((size_t)NN*4);
    int*    csr_s  = (int*)   alloc((size_t)NE*4);
    __half* ph     = (__half*)alloc((size_t)NN*64*2);   // fp16 message matrix P
    float*  gA     = (float*) alloc((size_t)NN*64*4);
    float*  gB     = (float*) alloc((size_t)NN*64*4);
    int2*   bins   = (int2*)  gA;    // bins dead before aggs writes gA

    hipMemsetAsync(binCnt, 0, (size_t)2*NBIN*PAD*4, stream);
    binA_k<<<(NE + 2047)/2048, 256, 0, stream>>>(e32, binCnt);
    binC_k<<<(NE + EPB - 1)/EPB, 256, 0, stream>>>(e32, binCnt, binCur, bins);
    binD_k<<<NBIN, 256, 0, stream>>>(bins, binCnt, rp, dinv, csr_s);

    const int GEMM_GRID = (NN + 63)/64;        // 1563
    const int AGGS_GRID = NN/2;                // 50000 (2 nodes/block, 2 waves/node)
    const int AGG_GRID  = (NN*64 + 255)/256;   // 25000

    gemm_k<128,64,64,false><<<GEMM_GRID, 256, 0, stream>>>(x,  W1, dinv, ph, NN);
    aggs_k<<<AGGS_GRID, 256, 0, stream>>>(ph, rp, csr_s, dinv, b1, gA);
    gemm_k<64,64,64,true><<<GEMM_GRID, 256, 0, stream>>>(gA, W2, dinv, ph, NN);
    aggs_k<<<AGGS_GRID, 256, 0, stream>>>(ph, rp, csr_s, dinv, b2, gB);
    gemm_k<64,40,64,true><<<GEMM_GRID, 256, 0, stream>>>(gB, W3, dinv, ph, NN);
    agg40_k<<<AGG_GRID, 256, 0, stream>>>(ph, rp, csr_s, dinv, b3, out);
}

// Round 9
// 244.009 us; speedup vs baseline: 1.2506x; 1.2506x over previous
//
#include <hip/hip_runtime.h>
#include <hip/hip_fp16.h>

#define NN 100000
#define NE 1250000
#define NBIN 512
#define RBIN 196          // ceil(NN/NBIN); bin b covers nodes [b*196, b*196+196)
#define PAD 16            // counter padding: 16 ints = 64B line
#define CAP 4096          // binD LDS edge-staging capacity (int2 = 32KB)
#define EPB 4096          // binC edges per block
#define EPT 16            // EPB/256
#define BCAP 3072         // fixed per-bin capacity (mean 2441 + 13 sigma)

__device__ __forceinline__ int eidx(const int* __restrict__ e32, int f, int i){
    return f ? e32[2*(size_t)i] : e32[i];
}

// one-wave exclusive scan of the 512 global bin counters into LDS boff[]
__device__ __forceinline__ void scan_bins(const int* __restrict__ cnts, int* __restrict__ boff){
    if(threadIdx.x < 64){
        int b0 = threadIdx.x*8;
        int pre[8]; int run = 0;
        #pragma unroll
        for(int i = 0; i < 8; ++i){ pre[i] = run; run += cnts[(b0+i)*PAD]; }
        int inc = run;
        for(int o = 1; o < 64; o <<= 1){
            int u = __shfl_up(inc, o, 64);
            if(threadIdx.x >= (unsigned)o) inc += u;
        }
        int excl = inc - run;
        #pragma unroll
        for(int i = 0; i < 8; ++i) boff[b0+i] = excl + pre[i];
    }
    __syncthreads();
}

// ---------------- pass C: block multi-split scatter into fixed-capacity dst-bins ----------------
__global__ __launch_bounds__(256) void binC_k(const int* __restrict__ e32,
                                              int* __restrict__ binCur, int2* __restrict__ bins){
    __shared__ int2 ST[EPB];          // 32KB staged edges, grouped by bin
    __shared__ int hist[NBIN];
    __shared__ int lstart[NBIN];
    __shared__ int gbase[NBIN];
    __shared__ int cur[NBIN];
    __shared__ int flg;
    const int t = threadIdx.x;
    const int e0 = blockIdx.x * EPB;
    const int n = min(EPB, NE - e0);

    for(int b = t; b < NBIN; b += 256){ hist[b] = 0; cur[b] = 0; }
    if(t < 64){
        int v = e32[2*t + 1];
        unsigned long long b = __ballot(v != 0);
        if(t == 0) flg = (b == 0ULL) ? 1 : 0;
    }
    __syncthreads();
    const int f = flg;

    // load edges to registers + LDS histogram
    int2 ed[EPT];
    #pragma unroll
    for(int k = 0; k < EPT; ++k){
        int i = k*256 + t;
        if(i < n){
            ed[k].x = eidx(e32, f, e0 + i);
            ed[k].y = eidx(e32, f, NE + e0 + i);
            atomicAdd(&hist[ed[k].y / RBIN], 1);
        }
    }
    __syncthreads();

    // single-wave exclusive scan of block-local hist
    if(t < 64){
        int b0 = t*8;
        int pre[8]; int run = 0;
        #pragma unroll
        for(int i = 0; i < 8; ++i){ pre[i] = run; run += hist[b0 + i]; }
        int inc = run;
        for(int o = 1; o < 64; o <<= 1){
            int u = __shfl_up(inc, o, 64);
            if(t >= o) inc += u;
        }
        int excl = inc - run;
        #pragma unroll
        for(int i = 0; i < 8; ++i) lstart[b0 + i] = excl + pre[i];
    }
    // reserve contiguous ranges at fixed per-bin bases (one atomic per bin per block)
    for(int b = t; b < NBIN; b += 256) gbase[b] = b*BCAP + atomicAdd(&binCur[b*PAD], hist[b]);
    __syncthreads();

    // scatter into LDS grouped by bin
    #pragma unroll
    for(int k = 0; k < EPT; ++k){
        int i = k*256 + t;
        if(i < n){
            int b = ed[k].y / RBIN;
            int lo = atomicAdd(&cur[b], 1);
            ST[lstart[b] + lo] = ed[k];
        }
    }
    __syncthreads();

    // linear copy-out: consecutive staged entries in a bin -> consecutive global slots
    for(int i = t; i < n; i += 256){
        int2 e = ST[i];
        int b = e.y / RBIN;
        bins[gbase[b] + (i - lstart[b])] = e;
    }
}

// ---------------- pass D: per-bin CSR build (rp, dinv, csr_src), inline scan of counts ----------------
__global__ __launch_bounds__(256) void binD_k(const int2* __restrict__ bins, const int* __restrict__ binCur,
                                              int* __restrict__ rp, float* __restrict__ dinv,
                                              int* __restrict__ csr_src){
    __shared__ int2 ES[CAP];
    __shared__ int hist[256];
    __shared__ int sc[256];
    __shared__ int cur[256];
    __shared__ int boff[NBIN];
    const int b = blockIdx.x;
    const int t = threadIdx.x;
    if(b == NBIN-1 && t == 0) rp[NN] = NE;
    const int nbase = b * RBIN;
    if(nbase >= NN) return;                      // empty trailing bin
    const int nend = min(nbase + RBIN, NN);
    const int nr = nend - nbase;
    hist[t] = 0; cur[t] = 0;
    __syncthreads();
    scan_bins(binCur, boff);                     // compact global offsets from final counts
    const int off0 = boff[b];                    // compact csr offset
    const int rb   = b * BCAP;                   // bins read base
    const int cnt  = binCur[b*PAD];

    const bool single = (cnt <= CAP);
    // histogram phase
    for(int c0 = 0; c0 < cnt; c0 += CAP){
        int n = min(CAP, cnt - c0);
        for(int i = t; i < n; i += 256) ES[i] = bins[rb + c0 + i];
        __syncthreads();
        for(int i = t; i < n; i += 256) atomicAdd(&hist[ES[i].y - nbase], 1);
        __syncthreads();
    }
    // exclusive scan of hist into sc
    int v = hist[t];
    sc[t] = v; __syncthreads();
    for(int off = 1; off < 256; off <<= 1){
        int u = (t >= off) ? sc[t - off] : 0;
        __syncthreads();
        sc[t] += u;
        __syncthreads();
    }
    int excl = sc[t] - v;
    sc[t] = excl;
    if(t < nr){
        rp[nbase + t]   = off0 + excl;
        dinv[nbase + t] = rsqrtf((float)(v + 1));   // +1 = self loop
    }
    __syncthreads();
    // scatter phase (ES still valid if single chunk)
    for(int c0 = 0; c0 < cnt; c0 += CAP){
        int n = min(CAP, cnt - c0);
        if(!single){
            for(int i = t; i < n; i += 256) ES[i] = bins[rb + c0 + i];
            __syncthreads();
        }
        for(int i = t; i < n; i += 256){
            int dl = ES[i].y - nbase;
            int p = atomicAdd(&cur[dl], 1);
            csr_src[off0 + sc[dl] + p] = ES[i].x;
        }
        if(!single) __syncthreads();
    }
}

// ---------------- dense GEMM, K-tiled: out[row] = fp16( (A@W)[row] * dinv[row] ) ----------------
// AHALF: A is __half (converted to fp32 in staging). OSTR: output row stride in halfs.
template<bool AHALF, int K, int NC, int KT, int OSTR, bool RELU>
__global__ __launch_bounds__(256) void gemm_k(const void* __restrict__ Araw, const float* __restrict__ W,
                                              const float* __restrict__ dinv,
                                              __half* __restrict__ out, int M){
    constexpr int CHT = KT/4;          // float4 chunks per row per K-tile
    constexpr int CMASK = CHT - 1;
    __shared__ float Xs[64*KT];
    __shared__ float Ws[KT*NC];
    const int tid  = threadIdx.x;
    const int base = blockIdx.x * 64;
    const int tx = tid & 15, ty = tid >> 4;
    const int c0 = tx * 4;
    float acc[4][4] = {};

    for(int k0 = 0; k0 < K; k0 += KT){
        {
            const float4* Wv = (const float4*)(W + k0*NC);
            float4* Wsv = (float4*)Ws;
            for(int i = tid; i < KT*NC/4; i += 256) Wsv[i] = Wv[i];
        }
        {
            const int ch = tid & (CHT - 1);
            const int r0 = tid / CHT;
            constexpr int RSTEP = 256 / CHT;
            #pragma unroll
            for(int r = r0; r < 64; r += RSTEP){
                int row = base + r; if(row >= M) row = M - 1;
                float4 v;
                if(AHALF){
                    const __half2* ap = (const __half2*)((const __half*)Araw + (size_t)row*K + k0 + ch*4);
                    float2 fa = __half22float2(ap[0]), fb = __half22float2(ap[1]);
                    v = make_float4(fa.x, fa.y, fb.x, fb.y);
                } else {
                    v = *(const float4*)((const float*)Araw + (size_t)row*K + k0 + ch*4);
                }
                if(RELU){ v.x=fmaxf(v.x,0.f); v.y=fmaxf(v.y,0.f); v.z=fmaxf(v.z,0.f); v.w=fmaxf(v.w,0.f); }
                int sw = (ch + r) & CMASK;
                *(float4*)&Xs[r*KT + sw*4] = v;
            }
        }
        __syncthreads();

        if(c0 < NC){
            for(int k4 = 0; k4 < CHT; ++k4){
                float4 xs[4];
                #pragma unroll
                for(int i = 0; i < 4; ++i){
                    int r = ty*4 + i;
                    int sw = (k4 + r) & CMASK;
                    xs[i] = *(const float4*)&Xs[r*KT + (sw << 2)];
                }
                float4 wsv[4];
                #pragma unroll
                for(int kk = 0; kk < 4; ++kk) wsv[kk] = *(const float4*)&Ws[(k4*4 + kk)*NC + c0];
                #pragma unroll
                for(int kk = 0; kk < 4; ++kk){
                    const float* wp = (const float*)&wsv[kk];
                    #pragma unroll
                    for(int i = 0; i < 4; ++i){
                        float xv = ((const float*)&xs[i])[kk];
                        #pragma unroll
                        for(int j = 0; j < 4; ++j) acc[i][j] += xv * wp[j];
                    }
                }
            }
        }
        __syncthreads();
    }
    #pragma unroll
    for(int i = 0; i < 4; ++i){
        int row = base + ty*4 + i;
        if(row < M && c0 < NC){
            float dv = dinv[row];
            __half2 h01 = __floats2half2_rn(acc[i][0]*dv, acc[i][1]*dv);
            __half2 h23 = __floats2half2_rn(acc[i][2]*dv, acc[i][3]*dv);
            __half2* dst = (__half2*)&out[(size_t)row*OSTR + c0];
            dst[0] = h01;
            dst[1] = h23;
        }
    }
}

// ---------------- CSR aggregation F=64 -> fp16 G: 16 lanes/edge, 4 edges/wave-instr ----------------
// G[v] = fp16( b + dinv[v]*(sum P[s] + P[v]) ); P fp16 pre-scaled by dinv; fp32 accum.
__global__ __launch_bounds__(256) void agg64_k(const __half* __restrict__ P, const int* __restrict__ rp,
                                               const int* __restrict__ csr_src,
                                               const float* __restrict__ dinv, const float* __restrict__ bias,
                                               __half* __restrict__ G){
    constexpr unsigned F2 = 32;                   // half2 per row
    const int lane = threadIdx.x & 63;
    const int v = (blockIdx.x*256 + threadIdx.x) >> 6;
    if(v >= NN) return;
    const int g = lane >> 4;                      // edge-group 0..3
    const int q = lane & 15;                      // channel-quad
    const unsigned qo = (unsigned)q*2;
    const __half2* __restrict__ P2 = (const __half2*)P;

    const int beg = rp[v], end = rp[v + 1];
    float4 acc = make_float4(0.f, 0.f, 0.f, 0.f);
    if(g == 0){                                   // self-loop term
        __half2 a = P2[(unsigned)v*F2 + qo], b = P2[(unsigned)v*F2 + qo + 1];
        float2 fa = __half22float2(a), fb = __half22float2(b);
        acc = make_float4(fa.x, fa.y, fb.x, fb.y);
    }

    int j = beg;
    #pragma unroll 1
    for(; j + 16 <= end; j += 16){
        unsigned i0 = (unsigned)csr_src[j + g]     *F2 + qo;
        unsigned i1 = (unsigned)csr_src[j + 4 + g] *F2 + qo;
        unsigned i2 = (unsigned)csr_src[j + 8 + g] *F2 + qo;
        unsigned i3 = (unsigned)csr_src[j + 12 + g]*F2 + qo;
        __half2 a0 = P2[i0], b0 = P2[i0+1];
        __half2 a1 = P2[i1], b1 = P2[i1+1];
        __half2 a2 = P2[i2], b2 = P2[i2+1];
        __half2 a3 = P2[i3], b3 = P2[i3+1];
        __half2 sa = __hadd2(a0, a1), sb = __hadd2(b0, b1);
        __half2 ta = __hadd2(a2, a3), tb = __hadd2(b2, b3);
        float2 f0 = __half22float2(sa), f1 = __half22float2(sb);
        float2 f2 = __half22float2(ta), f3 = __half22float2(tb);
        acc.x += f0.x + f2.x; acc.y += f0.y + f2.y;
        acc.z += f1.x + f3.x; acc.w += f1.y + f3.y;
    }
    if(j + 8 <= end){
        unsigned i0 = (unsigned)csr_src[j + g]    *F2 + qo;
        unsigned i1 = (unsigned)csr_src[j + 4 + g]*F2 + qo;
        __half2 a0 = P2[i0], b0 = P2[i0+1];
        __half2 a1 = P2[i1], b1 = P2[i1+1];
        __half2 sa = __hadd2(a0, a1), sb = __hadd2(b0, b1);
        float2 f0 = __half22float2(sa), f1 = __half22float2(sb);
        acc.x += f0.x; acc.y += f0.y; acc.z += f1.x; acc.w += f1.y;
        j += 8;
    }
    if(j + 4 <= end){
        unsigned i0 = (unsigned)csr_src[j + g]*F2 + qo;
        __half2 a = P2[i0], b = P2[i0+1];
        float2 fa = __half22float2(a), fb = __half22float2(b);
        acc.x += fa.x; acc.y += fa.y; acc.z += fb.x; acc.w += fb.y;
        j += 4;
    }
    const int rem = end - j;                      // 0..3
    if(g < rem){
        unsigned i0 = (unsigned)csr_src[j + g]*F2 + qo;
        __half2 a = P2[i0], b = P2[i0+1];
        float2 fa = __half22float2(a), fb = __half22float2(b);
        acc.x += fa.x; acc.y += fa.y; acc.z += fb.x; acc.w += fb.y;
    }

    // reduce across the 4 edge-groups (butterfly over lane bits 4,5)
    #pragma unroll
    for(int m = 16; m <= 32; m <<= 1){
        acc.x += __shfl_xor(acc.x, m, 64);
        acc.y += __shfl_xor(acc.y, m, 64);
        acc.z += __shfl_xor(acc.z, m, 64);
        acc.w += __shfl_xor(acc.w, m, 64);
    }

    if(g == 0){
        const float d = dinv[v];
        float4 bb = *(const float4*)&bias[q*4];
        __half2 h01 = __floats2half2_rn(fmaf(acc.x, d, bb.x), fmaf(acc.y, d, bb.y));
        __half2 h23 = __floats2half2_rn(fmaf(acc.z, d, bb.z), fmaf(acc.w, d, bb.w));
        __half2* dst = (__half2*)&G[(size_t)v*64 + q*4];
        dst[0] = h01;
        dst[1] = h23;
    }
}

// ---------------- final CSR aggregation (F=40, padded stride 64) + fused log_softmax ----------------
__global__ __launch_bounds__(256) void agg40_k(const __half* __restrict__ P, const int* __restrict__ rp,
                                               const int* __restrict__ csr_src,
                                               const float* __restrict__ dinv, const float* __restrict__ bias,
                                               float* __restrict__ G){
    constexpr int NQ = 10;
    constexpr unsigned F2 = 32;                   // padded half2 stride (128B rows)
    const int lane = threadIdx.x & 63;
    const int v = (blockIdx.x*256 + threadIdx.x) >> 6;
    if(v >= NN) return;
    const int g = lane >> 4;                      // edge-group 0..3
    const int q = lane & 15;                      // channel-quad
    const bool qa = (q < NQ);
    const unsigned qo = (unsigned)q*2;
    const __half2* __restrict__ P2 = (const __half2*)P;

    const int beg = rp[v], end = rp[v + 1];
    float4 acc = make_float4(0.f, 0.f, 0.f, 0.f);
    if(g == 0 && qa){
        __half2 a = P2[(unsigned)v*F2 + qo], b = P2[(unsigned)v*F2 + qo + 1];
        float2 fa = __half22float2(a), fb = __half22float2(b);
        acc = make_float4(fa.x, fa.y, fb.x, fb.y);
    }

    int j = beg;
    #pragma unroll 1
    for(; j + 8 <= end; j += 8){
        unsigned i0 = (unsigned)csr_src[j + g]    *F2 + qo;
        unsigned i1 = (unsigned)csr_src[j + 4 + g]*F2 + qo;
        __half2 a0 = P2[i0], b0 = P2[i0+1];
        __half2 a1 = P2[i1], b1 = P2[i1+1];
        __half2 sa = __hadd2(a0, a1), sb = __hadd2(b0, b1);
        float2 f0 = __half22float2(sa), f1 = __half22float2(sb);
        acc.x += f0.x; acc.y += f0.y; acc.z += f1.x; acc.w += f1.y;
    }
    if(j + 4 <= end){
        unsigned i0 = (unsigned)csr_src[j + g]*F2 + qo;
        __half2 a = P2[i0], b = P2[i0+1];
        float2 fa = __half22float2(a), fb = __half22float2(b);
        acc.x += fa.x; acc.y += fa.y; acc.z += fb.x; acc.w += fb.y;
        j += 4;
    }
    const int rem = end - j;                      // 0..3
    if(g < rem){
        unsigned i0 = (unsigned)csr_src[j + g]*F2 + qo;
        __half2 a = P2[i0], b = P2[i0+1];
        float2 fa = __half22float2(a), fb = __half22float2(b);
        acc.x += fa.x; acc.y += fa.y; acc.z += fb.x; acc.w += fb.y;
    }

    #pragma unroll
    for(int m = 16; m <= 32; m <<= 1){
        acc.x += __shfl_xor(acc.x, m, 64);
        acc.y += __shfl_xor(acc.y, m, 64);
        acc.z += __shfl_xor(acc.z, m, 64);
        acc.w += __shfl_xor(acc.w, m, 64);
    }

    float4 r;
    const float d = dinv[v];
    if(g == 0 && qa){
        float4 bb = *(const float4*)&bias[q*4];
        r.x = fmaf(acc.x, d, bb.x);
        r.y = fmaf(acc.y, d, bb.y);
        r.z = fmaf(acc.z, d, bb.z);
        r.w = fmaf(acc.w, d, bb.w);
    }
    // fused log_softmax: butterfly over lane bits 0..3 (within 16-lane group); group 0 authoritative
    float lm = (g == 0 && qa) ? fmaxf(fmaxf(r.x, r.y), fmaxf(r.z, r.w)) : -3.402823466e38f;
    #pragma unroll
    for(int m = 1; m <= 8; m <<= 1) lm = fmaxf(lm, __shfl_xor(lm, m, 64));
    float ls = (g == 0 && qa)
             ? (__expf(r.x - lm) + __expf(r.y - lm) + __expf(r.z - lm) + __expf(r.w - lm)) : 0.0f;
    #pragma unroll
    for(int m = 1; m <= 8; m <<= 1) ls += __shfl_xor(ls, m, 64);
    if(g == 0 && qa){
        float lz = lm + __logf(ls);
        r.x -= lz; r.y -= lz; r.z -= lz; r.w -= lz;
        *(float4*)&G[(size_t)v*40 + q*4] = r;
    }
}

extern "C" void kernel_launch(void* const* d_in, const int* in_sizes, int n_in,
                              void* d_out, int out_size, void* d_ws, size_t ws_size,
                              hipStream_t stream){
    const float* x   = (const float*)d_in[0];
    const int*   e32 = (const int*)  d_in[1];
    const float* W1  = (const float*)d_in[2];
    const float* b1  = (const float*)d_in[3];
    const float* W2  = (const float*)d_in[4];
    const float* b2  = (const float*)d_in[5];
    const float* W3  = (const float*)d_in[6];
    const float* b3  = (const float*)d_in[7];
    float* out = (float*)d_out;

    char* ws = (char*)d_ws;
    size_t off = 0;
    auto alloc = [&](size_t bytes) -> void* {
        void* p = ws + off;
        off = (off + bytes + 255) & ~(size_t)255;
        return p;
    };
    int*    binCur = (int*)   alloc((size_t)NBIN*PAD*4);   // 32KB, zeroed
    int*    rp     = (int*)   alloc((size_t)(NN+1)*4);
    float*  dinv   = (float*) alloc((size_t)NN*4);
    int*    csr_s  = (int*)   alloc((size_t)NE*4);
    __half* ph     = (__half*)alloc((size_t)NN*64*2);   // fp16 message matrix P (stride 64 all layers)
    __half* gA     = (__half*)alloc((size_t)NN*64*2);   // fp16 intermediate G
    __half* gB     = (__half*)alloc((size_t)NN*64*2);
    int2*   bins   = (int2*)  alloc((size_t)NBIN*BCAP*8); // 12.6MB fixed-capacity bins

    hipMemsetAsync(binCur, 0, (size_t)NBIN*PAD*4, stream);
    binC_k<<<(NE + EPB - 1)/EPB, 256, 0, stream>>>(e32, binCur, bins);
    binD_k<<<NBIN, 256, 0, stream>>>(bins, binCur, rp, dinv, csr_s);

    const int GEMM_GRID = (NN + 63)/64;        // 1563
    const int AGG_GRID  = (NN*64 + 255)/256;   // 25000

    gemm_k<false,128,64,64,64,false><<<GEMM_GRID, 256, 0, stream>>>(x,  W1, dinv, ph, NN);
    agg64_k<<<AGG_GRID, 256, 0, stream>>>(ph, rp, csr_s, dinv, b1, gA);
    gemm_k<true, 64,64,64,64,true ><<<GEMM_GRID, 256, 0, stream>>>(gA, W2, dinv, ph, NN);
    agg64_k<<<AGG_GRID, 256, 0, stream>>>(ph, rp, csr_s, dinv, b2, gB);
    gemm_k<true, 64,40,64,64,true ><<<GEMM_GRID, 256, 0, stream>>>(gB, W3, dinv, ph, NN);
    agg40_k<<<AGG_GRID, 256, 0, stream>>>(ph, rp, csr_s, dinv, b3, out);
}